// Round 2
// baseline (553.423 us; speedup 1.0000x reference)
//
#include <hip/hip_runtime.h>

#define BATCH 8
#define SLEN  200
#define NNODE 512
#define C1    32
#define C2    64
#define NEDGE 2048
#define NEGV  -9000000000000000.0f

// ---------------------------------------------------------------------------
// Kernel 1: fused conv1 -> relu -> conv2 -> relu -> mean over S
// one block (256 threads) per (b, n) sequence
// ---------------------------------------------------------------------------
__global__ __launch_bounds__(256) void conv_fused_kernel(
    const float* __restrict__ x,    // (B, S, N*2) f32
    const float* __restrict__ w1,   // (32, 2, 5)
    const float* __restrict__ b1,   // (32,)
    const float* __restrict__ w2,   // (64, 32, 5)
    const float* __restrict__ b2,   // (64,)
    float* __restrict__ hmean)      // (B*N, 64)
{
    __shared__ float xs[2][SLEN + 4];
    __shared__ float h1[C1][SLEN + 4];
    __shared__ float w2t[160 * 32];     // [r][ocl], r = ic*5+k, one 32-oc pass
    __shared__ float red[C2][8];

    const int t   = threadIdx.x;
    const int blk = blockIdx.x;        // b*N + n
    const int b   = blk >> 9;
    const int n   = blk & 511;

    // stage x with zero padding (2 each side)
    if (t < SLEN) {
        const float* xp = x + ((size_t)(b * SLEN + t)) * (NNODE * 2) + n * 2;
        xs[0][2 + t] = xp[0];
        xs[1][2 + t] = xp[1];
    } else if (t < SLEN + 8) {
        int c = (t - SLEN) & 1;
        int p = (t - SLEN) >> 1;             // 0..3
        int pos = (p < 2) ? p : (SLEN + p);  // 0,1,202,203
        xs[c][pos] = 0.f;
    }
    if (t < C1) {
        h1[t][0] = 0.f; h1[t][1] = 0.f;
        h1[t][SLEN + 2] = 0.f; h1[t][SLEN + 3] = 0.f;
    }
    __syncthreads();

    // conv1: 32 oc x 8 s-groups
    {
        const int oc = t >> 3, sg = t & 7;
        float w[10];
        #pragma unroll
        for (int j = 0; j < 10; ++j) w[j] = w1[oc * 10 + j];
        const float bias = b1[oc];
        for (int i = 0; i < 25; ++i) {
            const int s = sg + 8 * i;
            float acc = bias;
            #pragma unroll
            for (int k = 0; k < 5; ++k)
                acc += w[k] * xs[0][s + k] + w[5 + k] * xs[1][s + k];
            h1[oc][2 + s] = fmaxf(acc, 0.f);
        }
    }
    __syncthreads();

    // conv2 + relu + running mean, two passes of 32 output channels
    const int ocl = t >> 3, sg = t & 7;
    for (int pass = 0; pass < 2; ++pass) {
        // stage this pass's weights transposed: w2t[r*32+ocl]
        for (int src = t; src < 32 * 160; src += 256) {
            int o = src / 160;
            int r = src - o * 160;
            w2t[r * 32 + o] = w2[(size_t)(pass * 32 + o) * 160 + r];
        }
        __syncthreads();

        const int oc = pass * 32 + ocl;
        const float bias = b2[oc];
        float acc[7][4];
        #pragma unroll
        for (int j = 0; j < 7; ++j) {
            acc[j][0] = bias; acc[j][1] = bias; acc[j][2] = bias; acc[j][3] = bias;
        }
        for (int ic = 0; ic < C1; ++ic) {
            const int rb = ic * 5;
            const float wk0 = w2t[(rb + 0) * 32 + ocl];
            const float wk1 = w2t[(rb + 1) * 32 + ocl];
            const float wk2 = w2t[(rb + 2) * 32 + ocl];
            const float wk3 = w2t[(rb + 3) * 32 + ocl];
            const float wk4 = w2t[(rb + 4) * 32 + ocl];
            #pragma unroll
            for (int j = 0; j < 7; ++j) {
                const int sb = sg + 8 * j;
                if (sb < 50) {
                    const int s0 = sb * 4;
                    const float4 v0 = *(const float4*)&h1[ic][s0];
                    const float4 v1 = *(const float4*)&h1[ic][s0 + 4];
                    acc[j][0] += wk0 * v0.x + wk1 * v0.y + wk2 * v0.z + wk3 * v0.w + wk4 * v1.x;
                    acc[j][1] += wk0 * v0.y + wk1 * v0.z + wk2 * v0.w + wk3 * v1.x + wk4 * v1.y;
                    acc[j][2] += wk0 * v0.z + wk1 * v0.w + wk2 * v1.x + wk3 * v1.y + wk4 * v1.z;
                    acc[j][3] += wk0 * v0.w + wk1 * v1.x + wk2 * v1.y + wk3 * v1.z + wk4 * v1.w;
                }
            }
        }
        float total = 0.f;
        #pragma unroll
        for (int j = 0; j < 7; ++j) {
            if (sg + 8 * j < 50)
                total += fmaxf(acc[j][0], 0.f) + fmaxf(acc[j][1], 0.f)
                       + fmaxf(acc[j][2], 0.f) + fmaxf(acc[j][3], 0.f);
        }
        red[oc][sg] = total;
        __syncthreads();
    }

    if (t < C2) {
        float m = 0.f;
        #pragma unroll
        for (int s = 0; s < 8; ++s) m += red[t][s];
        hmean[(size_t)blk * 64 + t] = m * (1.0f / 200.0f);
    }
}

// ---------------------------------------------------------------------------
// Kernel 2: Wh = h @ W ; f1 = Wh @ a[:64] ; f2 = Wh @ a[64:]
// one wave (64 threads) per row (b*N+n)
// ---------------------------------------------------------------------------
__global__ __launch_bounds__(64) void gat_wh_kernel(
    const float* __restrict__ h,     // (B*N, 64)
    const float* __restrict__ W,     // (64, 64)
    const float* __restrict__ a,     // (128, 1)
    float* __restrict__ Wh,          // (B*N, 64)
    float* __restrict__ f1,          // (B*N,)
    float* __restrict__ f2)          // (B*N,)
{
    __shared__ float hs[64];
    const int row = blockIdx.x;
    const int o = threadIdx.x;
    hs[o] = h[(size_t)row * 64 + o];
    __syncthreads();
    float acc = 0.f;
    #pragma unroll
    for (int f = 0; f < 64; ++f)
        acc += hs[f] * W[f * 64 + o];
    Wh[(size_t)row * 64 + o] = acc;
    float v1 = acc * a[o];
    float v2 = acc * a[64 + o];
    #pragma unroll
    for (int off = 32; off; off >>= 1) {
        v1 += __shfl_xor(v1, off, 64);
        v2 += __shfl_xor(v2, off, 64);
    }
    if (o == 0) { f1[row] = v1; f2[row] = v2; }
}

// ---------------------------------------------------------------------------
// Kernel 3: attention row: e = mask(leaky(f1_i + f2_j)); softmax; out = att@Wh
// one block (256 threads) per (b, i)
// ---------------------------------------------------------------------------
__global__ __launch_bounds__(256) void gat_attn_kernel(
    const float* __restrict__ Wh,    // (B*N, 64)
    const float* __restrict__ f1,
    const float* __restrict__ f2,
    const int* __restrict__ adj,     // (N, N)
    float* __restrict__ outp,        // (B*N, 64)
    const int do_relu)
{
    __shared__ float p[NNODE];
    __shared__ float smax[4];
    __shared__ float ssum[4];
    __shared__ float acc4[4][64];

    const int blk = blockIdx.x;      // b*N + i
    const int b = blk >> 9;
    const int i = blk & 511;
    const int t = threadIdx.x;

    const float f1i = f1[blk];
    const float* f2b = f2 + b * NNODE;
    const int* arow = adj + (size_t)i * NNODE;

    float e0, e1;
    {
        float e = f1i + f2b[t];
        e = e > 0.f ? e : 0.2f * e;
        e0 = (arow[t] > 0) ? e : NEGV;
        float g = f1i + f2b[t + 256];
        g = g > 0.f ? g : 0.2f * g;
        e1 = (arow[t + 256] > 0) ? g : NEGV;
    }
    float m = fmaxf(e0, e1);
    #pragma unroll
    for (int off = 32; off; off >>= 1) m = fmaxf(m, __shfl_xor(m, off, 64));
    if ((t & 63) == 0) smax[t >> 6] = m;
    __syncthreads();
    m = fmaxf(fmaxf(smax[0], smax[1]), fmaxf(smax[2], smax[3]));

    float ex0 = __expf(e0 - m);
    float ex1 = __expf(e1 - m);
    float s = ex0 + ex1;
    #pragma unroll
    for (int off = 32; off; off >>= 1) s += __shfl_xor(s, off, 64);
    if ((t & 63) == 0) ssum[t >> 6] = s;
    __syncthreads();
    const float inv = 1.0f / (ssum[0] + ssum[1] + ssum[2] + ssum[3]);
    p[t] = ex0 * inv;
    p[t + 256] = ex1 * inv;
    __syncthreads();

    // out[o] = sum_j p[j] * Wh[b, j, o]
    const int o = t & 63;
    const int jg = t >> 6;
    const float* WhB = Wh + (size_t)b * NNODE * 64;
    float acc = 0.f;
    const int j0 = jg * 128;
    for (int j = j0; j < j0 + 128; ++j)
        acc += p[j] * WhB[(size_t)j * 64 + o];
    acc4[jg][o] = acc;
    __syncthreads();
    if (t < 64) {
        float r = acc4[0][t] + acc4[1][t] + acc4[2][t] + acc4[3][t];
        if (do_relu) r = fmaxf(r, 0.f);
        outp[(size_t)blk * 64 + t] = r;
    }
}

// ---------------------------------------------------------------------------
// Kernel 4: edge gather + fc1 + relu + fc2 + sigmoid
// one wave per (b, e); 4 waves per block
// ---------------------------------------------------------------------------
__global__ __launch_bounds__(256) void edge_mlp_kernel(
    const float* __restrict__ hg,       // (B*N, 64) final GAT output
    const int* __restrict__ eidx,       // (E, 2)
    const float* __restrict__ fc1w,     // (128, 64)
    const float* __restrict__ fc1b,     // (64,)
    const float* __restrict__ fc2w,     // (64, 1)
    const float* __restrict__ fc2b,     // (1,)
    float* __restrict__ out)            // (B, E) f32
{
    __shared__ float he[4][128];
    const int t = threadIdx.x;
    const int w = t >> 6;
    const int o = t & 63;
    const int idx = blockIdx.x * 4 + w;       // in [0, B*E)
    const int b = idx >> 11;                  // / 2048
    const int e = idx & (NEDGE - 1);

    const int src = eidx[e * 2 + 0];
    const int dst = eidx[e * 2 + 1];
    const float* hb = hg + (size_t)b * NNODE * 64;
    he[w][o]      = hb[(size_t)src * 64 + o];
    he[w][64 + o] = hb[(size_t)dst * 64 + o];
    __syncthreads();

    float z = fc1b[o];
    #pragma unroll 8
    for (int k = 0; k < 128; ++k)
        z += he[w][k] * fc1w[k * 64 + o];
    z = fmaxf(z, 0.f);
    float r = z * fc2w[o];
    #pragma unroll
    for (int off = 32; off; off >>= 1) r += __shfl_xor(r, off, 64);
    if (o == 0) {
        float v = r + fc2b[0];
        out[idx] = 1.0f / (1.0f + __expf(-v));
    }
}

// ---------------------------------------------------------------------------
extern "C" void kernel_launch(void* const* d_in, const int* in_sizes, int n_in,
                              void* d_out, int out_size, void* d_ws, size_t ws_size,
                              hipStream_t stream) {
    const float* x    = (const float*)d_in[0];
    const int* adj    = (const int*)d_in[1];
    const int* eidx   = (const int*)d_in[2];
    const float* w1   = (const float*)d_in[3];
    const float* b1   = (const float*)d_in[4];
    const float* w2   = (const float*)d_in[5];
    const float* b2   = (const float*)d_in[6];
    const float* W1   = (const float*)d_in[7];
    const float* a1   = (const float*)d_in[8];
    const float* W2   = (const float*)d_in[9];
    const float* a2   = (const float*)d_in[10];
    const float* fc1w = (const float*)d_in[11];
    const float* fc1b = (const float*)d_in[12];
    const float* fc2w = (const float*)d_in[13];
    const float* fc2b = (const float*)d_in[14];
    float* out = (float*)d_out;

    float* ws = (float*)d_ws;
    const size_t R = (size_t)BATCH * NNODE;       // 4096 rows
    float* hmean = ws;                            // R*64
    float* Wh    = hmean + R * 64;                // R*64
    float* f1    = Wh + R * 64;                   // R
    float* f2    = f1 + R;                        // R
    float* g1    = f2 + R;                        // R*64
    float* g2    = hmean;                         // reuse (hmean dead after layer-1 Wh)

    conv_fused_kernel<<<dim3(R), dim3(256), 0, stream>>>(x, w1, b1, w2, b2, hmean);
    gat_wh_kernel<<<dim3(R), dim3(64), 0, stream>>>(hmean, W1, a1, Wh, f1, f2);
    gat_attn_kernel<<<dim3(R), dim3(256), 0, stream>>>(Wh, f1, f2, adj, g1, 1);
    gat_wh_kernel<<<dim3(R), dim3(64), 0, stream>>>(g1, W2, a2, Wh, f1, f2);
    gat_attn_kernel<<<dim3(R), dim3(256), 0, stream>>>(Wh, f1, f2, adj, g2, 0);
    edge_mlp_kernel<<<dim3((BATCH * NEDGE) / 4), dim3(256), 0, stream>>>(
        g2, eidx, fc1w, fc1b, fc2w, fc2b, out);
}

// Round 3
// 184.970 us; speedup vs baseline: 2.9920x; 2.9920x over previous
//
#include <hip/hip_runtime.h>

typedef unsigned short u16;
typedef __attribute__((ext_vector_type(8))) short short8;
typedef __attribute__((ext_vector_type(4))) float float4v;

#define BATCH 8
#define SLEN  200
#define NNODE 512
#define C1    32
#define C2    64
#define NEDGE 2048
#define NEGV  -9000000000000000.0f

#define H1S 40    // h1p row stride in bf16 elems (80 B = 16B-aligned, odd # of 16B units)
#define H1R 212   // rows: 2 zero-pad + 200 data + 10 zero-pad (covers m-tile 12 reads)

__device__ __forceinline__ u16 f2bf(float f) {
    unsigned int x = __float_as_uint(f);
    unsigned int lsb = (x >> 16) & 1u;
    x += 0x7fffu + lsb;
    return (u16)(x >> 16);
}

// ---------------------------------------------------------------------------
// Kernel 1: fused conv1 -> relu -> conv2(MFMA) -> relu -> mean over S
// one block (256 threads = 4 waves) per (b, n); wave w owns oc-tile w (16 oc)
// ---------------------------------------------------------------------------
__global__ __launch_bounds__(256) void conv_fused_kernel(
    const float* __restrict__ x,    // (B, S, N*2) f32
    const float* __restrict__ w1,   // (32, 2, 5)
    const float* __restrict__ b1,   // (32,)
    const float* __restrict__ w2,   // (64, 32, 5)
    const float* __restrict__ b2,   // (64,)
    float* __restrict__ hmean)      // (B*N, 64)
{
    __shared__ float xs[2][SLEN + 4];
    __shared__ __align__(16) u16 h1p[H1R * H1S];   // [s][ic] bf16, transposed conv1 out

    const int t    = threadIdx.x;
    const int blk  = blockIdx.x;        // b*N + n
    const int b    = blk >> 9;
    const int n    = blk & 511;
    const int lane = t & 63;
    const int wv   = t >> 6;            // wave id = oc-tile
    const int ml   = lane & 15;
    const int q    = lane >> 4;

    // ---- B fragments from global (L2-hot after first blocks):
    // B_kk[ic][oc], oc = wv*16+ml (n=lane&15), ic = q*8+j (k=q*8+j)
    short8 bfrag[5];
    {
        const float* wp = w2 + (size_t)(wv * 16 + ml) * 160 + (q * 8) * 5;
        #pragma unroll
        for (int kk = 0; kk < 5; ++kk) {
            #pragma unroll
            for (int j = 0; j < 8; ++j)
                bfrag[kk][j] = (short)f2bf(wp[j * 5 + kk]);
        }
    }
    const float bias2 = b2[wv * 16 + ml];

    // ---- stage x with zero padding (2 each side)
    if (t < SLEN) {
        const float* xp = x + ((size_t)(b * SLEN + t)) * (NNODE * 2) + n * 2;
        xs[0][2 + t] = xp[0];
        xs[1][2 + t] = xp[1];
    } else if (t < SLEN + 8) {
        int c = (t - SLEN) & 1;
        int p = (t - SLEN) >> 1;             // 0..3
        int pos = (p < 2) ? p : (SLEN + p);  // 0,1,202,203
        xs[c][pos] = 0.f;
    }
    // ---- zero h1p pad rows 0,1 and 202..211 (12 rows x 40 u16 = 240 dwords)
    {
        unsigned int* hz = (unsigned int*)h1p;
        if (t < 40)       hz[t] = 0u;
        else if (t < 240) hz[202 * (H1S / 2) + (t - 40)] = 0u;
    }
    __syncthreads();

    // ---- conv1: thread = (oc-pair p, s-group sg); writes bf16x2 to h1p[s][ic]
    {
        const int p  = t >> 4;    // 0..15 -> oc {2p, 2p+1}
        const int sg = t & 15;
        float wA[10], wB[10];
        #pragma unroll
        for (int j = 0; j < 10; ++j) {
            wA[j] = w1[(2 * p) * 10 + j];
            wB[j] = w1[(2 * p + 1) * 10 + j];
        }
        const float bA = b1[2 * p], bB = b1[2 * p + 1];
        for (int i = 0; i < 13; ++i) {
            const int s = sg + 16 * i;
            if (s < SLEN) {
                float a0 = bA, a1 = bB;
                #pragma unroll
                for (int k = 0; k < 5; ++k) {
                    const float x0 = xs[0][s + k], x1 = xs[1][s + k];
                    a0 += wA[k] * x0 + wA[5 + k] * x1;
                    a1 += wB[k] * x0 + wB[5 + k] * x1;
                }
                a0 = fmaxf(a0, 0.f);
                a1 = fmaxf(a1, 0.f);
                unsigned int pack = (unsigned int)f2bf(a0) | ((unsigned int)f2bf(a1) << 16);
                *(unsigned int*)&h1p[(2 + s) * H1S + 2 * p] = pack;
            }
        }
    }
    __syncthreads();

    // ---- conv2 as 5 tap-GEMMs on MFMA; fused bias+relu+mean epilogue
    float total = 0.f;
    for (int mt = 0; mt < 13; ++mt) {
        const int m0 = mt * 16;
        float4v acc = {0.f, 0.f, 0.f, 0.f};
        #pragma unroll
        for (int kk = 0; kk < 5; ++kk) {
            // A[m=ml][k=q*8+j] = h1p[m0+ml+kk][q*8+j] : one ds_read_b128
            const short8 a = *(const short8*)&h1p[(m0 + ml + kk) * H1S + q * 8];
            acc = __builtin_amdgcn_mfma_f32_16x16x32_bf16(a, bfrag[kk], acc, 0, 0, 0);
        }
        // C/D: col(oc) = lane&15, row(m) = q*4 + r
        #pragma unroll
        for (int r = 0; r < 4; ++r) {
            const int m = m0 + q * 4 + r;
            if (m < SLEN) total += fmaxf(acc[r] + bias2, 0.f);
        }
    }
    // reduce over the 4 quads (lanes ^16, ^32 share the same oc)
    total += __shfl_xor(total, 16, 64);
    total += __shfl_xor(total, 32, 64);
    if (lane < 16)
        hmean[(size_t)blk * 64 + wv * 16 + lane] = total * (1.0f / 200.0f);
}

// ---------------------------------------------------------------------------
// Kernel 2: Wh = h @ W ; f1 = Wh @ a[:64] ; f2 = Wh @ a[64:]
// one wave (64 threads) per row (b*N+n)
// ---------------------------------------------------------------------------
__global__ __launch_bounds__(64) void gat_wh_kernel(
    const float* __restrict__ h,     // (B*N, 64)
    const float* __restrict__ W,     // (64, 64)
    const float* __restrict__ a,     // (128, 1)
    float* __restrict__ Wh,          // (B*N, 64)
    float* __restrict__ f1,          // (B*N,)
    float* __restrict__ f2)          // (B*N,)
{
    __shared__ float hs[64];
    const int row = blockIdx.x;
    const int o = threadIdx.x;
    hs[o] = h[(size_t)row * 64 + o];
    __syncthreads();
    float acc = 0.f;
    #pragma unroll
    for (int f = 0; f < 64; ++f)
        acc += hs[f] * W[f * 64 + o];
    Wh[(size_t)row * 64 + o] = acc;
    float v1 = acc * a[o];
    float v2 = acc * a[64 + o];
    #pragma unroll
    for (int off = 32; off; off >>= 1) {
        v1 += __shfl_xor(v1, off, 64);
        v2 += __shfl_xor(v2, off, 64);
    }
    if (o == 0) { f1[row] = v1; f2[row] = v2; }
}

// ---------------------------------------------------------------------------
// Kernel 3: attention row: e = mask(leaky(f1_i + f2_j)); softmax; out = att@Wh
// one block (256 threads) per (b, i)
// ---------------------------------------------------------------------------
__global__ __launch_bounds__(256) void gat_attn_kernel(
    const float* __restrict__ Wh,    // (B*N, 64)
    const float* __restrict__ f1,
    const float* __restrict__ f2,
    const int* __restrict__ adj,     // (N, N)
    float* __restrict__ outp,        // (B*N, 64)
    const int do_relu)
{
    __shared__ float p[NNODE];
    __shared__ float smax[4];
    __shared__ float ssum[4];
    __shared__ float acc4[4][64];

    const int blk = blockIdx.x;      // b*N + i
    const int b = blk >> 9;
    const int i = blk & 511;
    const int t = threadIdx.x;

    const float f1i = f1[blk];
    const float* f2b = f2 + b * NNODE;
    const int* arow = adj + (size_t)i * NNODE;

    float e0, e1;
    {
        float e = f1i + f2b[t];
        e = e > 0.f ? e : 0.2f * e;
        e0 = (arow[t] > 0) ? e : NEGV;
        float g = f1i + f2b[t + 256];
        g = g > 0.f ? g : 0.2f * g;
        e1 = (arow[t + 256] > 0) ? g : NEGV;
    }
    float m = fmaxf(e0, e1);
    #pragma unroll
    for (int off = 32; off; off >>= 1) m = fmaxf(m, __shfl_xor(m, off, 64));
    if ((t & 63) == 0) smax[t >> 6] = m;
    __syncthreads();
    m = fmaxf(fmaxf(smax[0], smax[1]), fmaxf(smax[2], smax[3]));

    float ex0 = __expf(e0 - m);
    float ex1 = __expf(e1 - m);
    float s = ex0 + ex1;
    #pragma unroll
    for (int off = 32; off; off >>= 1) s += __shfl_xor(s, off, 64);
    if ((t & 63) == 0) ssum[t >> 6] = s;
    __syncthreads();
    const float inv = 1.0f / (ssum[0] + ssum[1] + ssum[2] + ssum[3]);
    p[t] = ex0 * inv;
    p[t + 256] = ex1 * inv;
    __syncthreads();

    // out[o] = sum_j p[j] * Wh[b, j, o]
    const int o = t & 63;
    const int jg = t >> 6;
    const float* WhB = Wh + (size_t)b * NNODE * 64;
    float acc = 0.f;
    const int j0 = jg * 128;
    for (int j = j0; j < j0 + 128; ++j)
        acc += p[j] * WhB[(size_t)j * 64 + o];
    acc4[jg][o] = acc;
    __syncthreads();
    if (t < 64) {
        float r = acc4[0][t] + acc4[1][t] + acc4[2][t] + acc4[3][t];
        if (do_relu) r = fmaxf(r, 0.f);
        outp[(size_t)blk * 64 + t] = r;
    }
}

// ---------------------------------------------------------------------------
// Kernel 4: edge gather + fc1 + relu + fc2 + sigmoid
// one wave per (b, e); 4 waves per block
// ---------------------------------------------------------------------------
__global__ __launch_bounds__(256) void edge_mlp_kernel(
    const float* __restrict__ hg,       // (B*N, 64) final GAT output
    const int* __restrict__ eidx,       // (E, 2)
    const float* __restrict__ fc1w,     // (128, 64)
    const float* __restrict__ fc1b,     // (64,)
    const float* __restrict__ fc2w,     // (64, 1)
    const float* __restrict__ fc2b,     // (1,)
    float* __restrict__ out)            // (B, E) f32
{
    __shared__ float he[4][128];
    const int t = threadIdx.x;
    const int w = t >> 6;
    const int o = t & 63;
    const int idx = blockIdx.x * 4 + w;       // in [0, B*E)
    const int b = idx >> 11;                  // / 2048
    const int e = idx & (NEDGE - 1);

    const int src = eidx[e * 2 + 0];
    const int dst = eidx[e * 2 + 1];
    const float* hb = hg + (size_t)b * NNODE * 64;
    he[w][o]      = hb[(size_t)src * 64 + o];
    he[w][64 + o] = hb[(size_t)dst * 64 + o];
    __syncthreads();

    float z = fc1b[o];
    #pragma unroll 8
    for (int k = 0; k < 128; ++k)
        z += he[w][k] * fc1w[k * 64 + o];
    z = fmaxf(z, 0.f);
    float r = z * fc2w[o];
    #pragma unroll
    for (int off = 32; off; off >>= 1) r += __shfl_xor(r, off, 64);
    if (o == 0) {
        float v = r + fc2b[0];
        out[idx] = 1.0f / (1.0f + __expf(-v));
    }
}

// ---------------------------------------------------------------------------
extern "C" void kernel_launch(void* const* d_in, const int* in_sizes, int n_in,
                              void* d_out, int out_size, void* d_ws, size_t ws_size,
                              hipStream_t stream) {
    const float* x    = (const float*)d_in[0];
    const int* adj    = (const int*)d_in[1];
    const int* eidx   = (const int*)d_in[2];
    const float* w1   = (const float*)d_in[3];
    const float* b1   = (const float*)d_in[4];
    const float* w2   = (const float*)d_in[5];
    const float* b2   = (const float*)d_in[6];
    const float* W1   = (const float*)d_in[7];
    const float* a1   = (const float*)d_in[8];
    const float* W2   = (const float*)d_in[9];
    const float* a2   = (const float*)d_in[10];
    const float* fc1w = (const float*)d_in[11];
    const float* fc1b = (const float*)d_in[12];
    const float* fc2w = (const float*)d_in[13];
    const float* fc2b = (const float*)d_in[14];
    float* out = (float*)d_out;

    float* ws = (float*)d_ws;
    const size_t R = (size_t)BATCH * NNODE;       // 4096 rows
    float* hmean = ws;                            // R*64
    float* Wh    = hmean + R * 64;                // R*64
    float* f1    = Wh + R * 64;                   // R
    float* f2    = f1 + R;                        // R
    float* g1    = f2 + R;                        // R*64
    float* g2    = hmean;                         // reuse (hmean dead after layer-1 Wh)

    conv_fused_kernel<<<dim3(R), dim3(256), 0, stream>>>(x, w1, b1, w2, b2, hmean);
    gat_wh_kernel<<<dim3(R), dim3(64), 0, stream>>>(hmean, W1, a1, Wh, f1, f2);
    gat_attn_kernel<<<dim3(R), dim3(256), 0, stream>>>(Wh, f1, f2, adj, g1, 1);
    gat_wh_kernel<<<dim3(R), dim3(64), 0, stream>>>(g1, W2, a2, Wh, f1, f2);
    gat_attn_kernel<<<dim3(R), dim3(256), 0, stream>>>(Wh, f1, f2, adj, g2, 0);
    edge_mlp_kernel<<<dim3((BATCH * NEDGE) / 4), dim3(256), 0, stream>>>(
        g2, eidx, fc1w, fc1b, fc2w, fc2b, out);
}

// Round 4
// 147.101 us; speedup vs baseline: 3.7622x; 1.2574x over previous
//
#include <hip/hip_runtime.h>

typedef unsigned short u16;
typedef __attribute__((ext_vector_type(8))) short short8;
typedef __attribute__((ext_vector_type(4))) float float4v;

#define BATCH 8
#define SLEN  200
#define NNODE 512
#define C1    32
#define C2    64
#define NEDGE 2048
#define NEGV  -9000000000000000.0f

#define H1S 40    // h1p row stride in bf16 elems (80 B)
#define H1R 212   // rows: 2 zero-pad + 200 data + 10 zero-pad

__device__ __forceinline__ u16 f2bf(float f) {
    unsigned int x = __float_as_uint(f);
    unsigned int lsb = (x >> 16) & 1u;
    x += 0x7fffu + lsb;
    return (u16)(x >> 16);
}

// ---------------------------------------------------------------------------
// Kernel 1: fused conv1 -> relu -> conv2(MFMA) -> relu -> mean over S
// (unchanged from round 3)
// ---------------------------------------------------------------------------
__global__ __launch_bounds__(256) void conv_fused_kernel(
    const float* __restrict__ x,
    const float* __restrict__ w1,
    const float* __restrict__ b1,
    const float* __restrict__ w2,
    const float* __restrict__ b2,
    float* __restrict__ hmean)
{
    __shared__ float xs[2][SLEN + 4];
    __shared__ __align__(16) u16 h1p[H1R * H1S];

    const int t    = threadIdx.x;
    const int blk  = blockIdx.x;
    const int b    = blk >> 9;
    const int n    = blk & 511;
    const int lane = t & 63;
    const int wv   = t >> 6;
    const int ml   = lane & 15;
    const int q    = lane >> 4;

    short8 bfrag[5];
    {
        const float* wp = w2 + (size_t)(wv * 16 + ml) * 160 + (q * 8) * 5;
        #pragma unroll
        for (int kk = 0; kk < 5; ++kk) {
            #pragma unroll
            for (int j = 0; j < 8; ++j)
                bfrag[kk][j] = (short)f2bf(wp[j * 5 + kk]);
        }
    }
    const float bias2 = b2[wv * 16 + ml];

    if (t < SLEN) {
        const float* xp = x + ((size_t)(b * SLEN + t)) * (NNODE * 2) + n * 2;
        xs[0][2 + t] = xp[0];
        xs[1][2 + t] = xp[1];
    } else if (t < SLEN + 8) {
        int c = (t - SLEN) & 1;
        int p = (t - SLEN) >> 1;
        int pos = (p < 2) ? p : (SLEN + p);
        xs[c][pos] = 0.f;
    }
    {
        unsigned int* hz = (unsigned int*)h1p;
        if (t < 40)       hz[t] = 0u;
        else if (t < 240) hz[202 * (H1S / 2) + (t - 40)] = 0u;
    }
    __syncthreads();

    {
        const int p  = t >> 4;
        const int sg = t & 15;
        float wA[10], wB[10];
        #pragma unroll
        for (int j = 0; j < 10; ++j) {
            wA[j] = w1[(2 * p) * 10 + j];
            wB[j] = w1[(2 * p + 1) * 10 + j];
        }
        const float bA = b1[2 * p], bB = b1[2 * p + 1];
        for (int i = 0; i < 13; ++i) {
            const int s = sg + 16 * i;
            if (s < SLEN) {
                float a0 = bA, a1 = bB;
                #pragma unroll
                for (int k = 0; k < 5; ++k) {
                    const float x0 = xs[0][s + k], x1 = xs[1][s + k];
                    a0 += wA[k] * x0 + wA[5 + k] * x1;
                    a1 += wB[k] * x0 + wB[5 + k] * x1;
                }
                a0 = fmaxf(a0, 0.f);
                a1 = fmaxf(a1, 0.f);
                unsigned int pack = (unsigned int)f2bf(a0) | ((unsigned int)f2bf(a1) << 16);
                *(unsigned int*)&h1p[(2 + s) * H1S + 2 * p] = pack;
            }
        }
    }
    __syncthreads();

    float total = 0.f;
    for (int mt = 0; mt < 13; ++mt) {
        const int m0 = mt * 16;
        float4v acc = {0.f, 0.f, 0.f, 0.f};
        #pragma unroll
        for (int kk = 0; kk < 5; ++kk) {
            const short8 a = *(const short8*)&h1p[(m0 + ml + kk) * H1S + q * 8];
            acc = __builtin_amdgcn_mfma_f32_16x16x32_bf16(a, bfrag[kk], acc, 0, 0, 0);
        }
        #pragma unroll
        for (int r = 0; r < 4; ++r) {
            const int m = m0 + q * 4 + r;
            if (m < SLEN) total += fmaxf(acc[r] + bias2, 0.f);
        }
    }
    total += __shfl_xor(total, 16, 64);
    total += __shfl_xor(total, 32, 64);
    if (lane < 16)
        hmean[(size_t)blk * 64 + wv * 16 + lane] = total * (1.0f / 200.0f);
}

// ---------------------------------------------------------------------------
// Kernel 2 v2: MFMA Wh = h @ W over 64-row tiles; emits Wh^T bf16 [b][o][node]
// plus fused f1 = Wh@a[:64], f2 = Wh@a[64:]. Grid: 64 blocks x 256 thr.
// ---------------------------------------------------------------------------
__global__ __launch_bounds__(256) void gat_wh_kernel(
    const float* __restrict__ h,     // (4096, 64)
    const float* __restrict__ W,     // (64, 64)
    const float* __restrict__ a,     // (128, 1)
    u16* __restrict__ Wh_bt,         // (8, 64, 512) bf16 [b][o][node]
    float* __restrict__ f1,          // (4096,)
    float* __restrict__ f2)          // (4096,)
{
    __shared__ __align__(16) u16 hA[64 * 72];   // [row j'][k] pad->36dw%32=4
    __shared__ __align__(16) u16 Wt[64 * 72];   // [o][k]
    __shared__ __align__(16) u16 whT[64 * 72];  // [o][j']
    __shared__ float as[128];

    const int t    = threadIdx.x;
    const int blk  = blockIdx.x;       // b = blk>>3, chunk = blk&7
    const int b    = blk >> 3;
    const int j0   = (blk & 7) * 64;
    const int lane = t & 63, wv = t >> 6, ml = lane & 15, q = lane >> 4;

    // stage h rows (f32 -> bf16)
    {
        const int r = t >> 2, c0 = (t & 3) * 16;
        const float* hp = h + ((size_t)(b * 512 + j0 + r)) * 64 + c0;
        #pragma unroll
        for (int v = 0; v < 4; ++v) {
            float4 f = *(const float4*)(hp + v * 4);
            u16* dst = &hA[r * 72 + c0 + v * 4];
            dst[0] = f2bf(f.x); dst[1] = f2bf(f.y);
            dst[2] = f2bf(f.z); dst[3] = f2bf(f.w);
        }
    }
    // stage W transposed: Wt[o][k]
    {
        const int k = t >> 2, o0 = (t & 3) * 16;
        const float* wp = W + k * 64 + o0;
        #pragma unroll
        for (int v = 0; v < 16; ++v)
            Wt[(o0 + v) * 72 + k] = f2bf(wp[v]);
    }
    if (t < 128) as[t] = a[t];
    __syncthreads();

    // wave wv = m-tile (rows j' in [16wv, 16wv+16))
    short8 af0 = *(const short8*)&hA[(16 * wv + ml) * 72 + q * 8];
    short8 af1 = *(const short8*)&hA[(16 * wv + ml) * 72 + 32 + q * 8];
    float4v acc[4];
    #pragma unroll
    for (int nt = 0; nt < 4; ++nt) {
        short8 b0 = *(const short8*)&Wt[(16 * nt + ml) * 72 + q * 8];
        short8 b1 = *(const short8*)&Wt[(16 * nt + ml) * 72 + 32 + q * 8];
        float4v c = {0.f, 0.f, 0.f, 0.f};
        c = __builtin_amdgcn_mfma_f32_16x16x32_bf16(af0, b0, c, 0, 0, 0);
        c = __builtin_amdgcn_mfma_f32_16x16x32_bf16(af1, b1, c, 0, 0, 0);
        acc[nt] = c;
    }

    // epilogue 1: whT[o][j'] bf16 + f1/f2 via quad-shuffles
    #pragma unroll
    for (int nt = 0; nt < 4; ++nt)
        #pragma unroll
        for (int r = 0; r < 4; ++r)
            whT[(16 * nt + ml) * 72 + 16 * wv + q * 4 + r] = f2bf(acc[nt][r]);

    #pragma unroll
    for (int r = 0; r < 4; ++r) {
        float v1 = 0.f, v2 = 0.f;
        #pragma unroll
        for (int nt = 0; nt < 4; ++nt) {
            const float w = acc[nt][r];
            v1 += w * as[16 * nt + ml];
            v2 += w * as[64 + 16 * nt + ml];
        }
        v1 += __shfl_xor(v1, 1, 64); v2 += __shfl_xor(v2, 1, 64);
        v1 += __shfl_xor(v1, 2, 64); v2 += __shfl_xor(v2, 2, 64);
        v1 += __shfl_xor(v1, 4, 64); v2 += __shfl_xor(v2, 4, 64);
        v1 += __shfl_xor(v1, 8, 64); v2 += __shfl_xor(v2, 8, 64);
        if (ml == 0) {
            const int j = j0 + 16 * wv + q * 4 + r;
            f1[b * 512 + j] = v1;
            f2[b * 512 + j] = v2;
        }
    }
    __syncthreads();

    // epilogue 2: cooperative coalesced global write of Wh^T
    {
        const int o = t >> 2, js = (t & 3) * 16;
        u16* dst = Wh_bt + ((size_t)(b * 64 + o)) * 512 + j0 + js;
        *(short8*)dst = *(const short8*)&whT[o * 72 + js];
    }
}

// ---------------------------------------------------------------------------
// Kernel 3 v2: attention, 16-row i-tiles. Grid: 256 blocks x 256 thr.
// P = exp(masked leaky(f1_i+f2_j) - max) bf16 in LDS; out = (P @ Wh) * inv
// ---------------------------------------------------------------------------
#define PSTR 520
__global__ __launch_bounds__(256) void gat_attn_kernel(
    const u16* __restrict__ Wh_bt,   // (8, 64, 512) bf16
    const float* __restrict__ f1,
    const float* __restrict__ f2,
    const int* __restrict__ adj,     // (512, 512)
    float* __restrict__ outp,        // (4096, 64) f32
    const int do_relu)
{
    __shared__ __align__(16) u16 P[16 * PSTR];
    __shared__ float f2s[512];
    __shared__ float invs[16];
    __shared__ float f1s[16];

    const int t   = threadIdx.x;
    const int blk = blockIdx.x;       // b = blk>>5, it = blk&31
    const int b   = blk >> 5;
    const int i0  = (blk & 31) * 16;

    f2s[t]       = f2[b * 512 + t];
    f2s[256 + t] = f2[b * 512 + 256 + t];
    if (t < 16) f1s[t] = f1[b * 512 + i0 + t];
    __syncthreads();

    // phase 1: e + softmax stats; thread = (i = t>>4, jseg = t&15) -> 32 j's
    {
        const int i = t >> 4, jseg = t & 15;
        const float f1i = f1s[i];
        const int* arow = adj + (size_t)(i0 + i) * 512 + jseg * 32;
        const float* f2p = f2s + jseg * 32;
        float ev[32];
        float mx = -3.0e38f;
        #pragma unroll
        for (int v = 0; v < 8; ++v) {
            const int4 a4 = *(const int4*)(arow + v * 4);
            #pragma unroll
            for (int u = 0; u < 4; ++u) {
                const int m = (&a4.x)[u];
                float e = f1i + f2p[v * 4 + u];
                e = e > 0.f ? e : 0.2f * e;
                e = (m > 0) ? e : NEGV;
                ev[v * 4 + u] = e;
                mx = fmaxf(mx, e);
            }
        }
        mx = fmaxf(mx, __shfl_xor(mx, 1, 64));
        mx = fmaxf(mx, __shfl_xor(mx, 2, 64));
        mx = fmaxf(mx, __shfl_xor(mx, 4, 64));
        mx = fmaxf(mx, __shfl_xor(mx, 8, 64));
        float sum = 0.f;
        #pragma unroll
        for (int v = 0; v < 32; ++v) {
            const float ex = __expf(ev[v] - mx);
            ev[v] = ex;
            sum += ex;
        }
        sum += __shfl_xor(sum, 1, 64);
        sum += __shfl_xor(sum, 2, 64);
        sum += __shfl_xor(sum, 4, 64);
        sum += __shfl_xor(sum, 8, 64);
        if (jseg == 0) invs[i] = 1.0f / sum;
        u16* prow = &P[i * PSTR + jseg * 32];
        #pragma unroll
        for (int v = 0; v < 16; ++v) {
            const unsigned int pk = (unsigned int)f2bf(ev[2 * v])
                                  | ((unsigned int)f2bf(ev[2 * v + 1]) << 16);
            *(unsigned int*)&prow[2 * v] = pk;
        }
    }
    __syncthreads();

    // phase 2: out(16 x 64) = P(16x512) @ Wh(512x64); wave = 16-o n-tile
    const int lane = t & 63, wv = t >> 6, ml = lane & 15, q = lane >> 4;
    const u16* Bp = Wh_bt + ((size_t)(b * 64 + 16 * wv + ml)) * 512 + q * 8;
    float4v acc = {0.f, 0.f, 0.f, 0.f};
    for (int ks = 0; ks < 16; ++ks) {
        const short8 afr = *(const short8*)&P[ml * PSTR + ks * 32 + q * 8];
        const short8 bfr = *(const short8*)(Bp + ks * 32);
        acc = __builtin_amdgcn_mfma_f32_16x16x32_bf16(afr, bfr, acc, 0, 0, 0);
    }
    #pragma unroll
    for (int r = 0; r < 4; ++r) {
        const int i2 = q * 4 + r;
        float val = acc[r] * invs[i2];
        if (do_relu) val = fmaxf(val, 0.f);
        outp[((size_t)(b * 512 + i0 + i2)) * 64 + 16 * wv + ml] = val;
    }
}

// ---------------------------------------------------------------------------
// Kernel 4 v2: edge MLP via MFMA, 16 edges/block. Grid: 1024 blocks x 256 thr.
// ---------------------------------------------------------------------------
#define FSTR 136
__global__ __launch_bounds__(256) void edge_mlp_kernel(
    const float* __restrict__ hg,       // (4096, 64)
    const int* __restrict__ eidx,       // (2048, 2)
    const float* __restrict__ fc1w,     // (128, 64)
    const float* __restrict__ fc1b,     // (64,)
    const float* __restrict__ fc2w,     // (64, 1)
    const float* __restrict__ fc2b,     // (1,)
    float* __restrict__ out)            // (8, 2048)
{
    __shared__ __align__(16) u16 fwT[64 * FSTR];   // [o][k]
    __shared__ __align__(16) u16 he[16 * FSTR];    // [edge][k]
    __shared__ float part[16][4];
    __shared__ float b1s[64], w2s[64];

    const int t   = threadIdx.x;
    const int blk = blockIdx.x;        // b = blk>>7, e0 = (blk&127)*16
    const int b   = blk >> 7;
    const int e0  = (blk & 127) * 16;

    // stage fc1w transposed bf16
    {
        const int k = t >> 1, o0 = (t & 1) * 32;
        const float* wp = fc1w + k * 64 + o0;
        #pragma unroll
        for (int v = 0; v < 32; ++v)
            fwT[(o0 + v) * FSTR + k] = f2bf(wp[v]);
    }
    if (t < 64) { b1s[t] = fc1b[t]; w2s[t] = fc2w[t]; }
    // stage gathered edge features bf16
    {
        const int ep = t >> 4, p = t & 15;
        const int e = e0 + ep;
        const int node = (p < 8) ? eidx[e * 2] : eidx[e * 2 + 1];
        const int c0 = (p & 7) * 8;
        const float* hp = hg + ((size_t)(b * 512 + node)) * 64 + c0;
        const float4 fa = *(const float4*)hp;
        const float4 fb = *(const float4*)(hp + 4);
        u16* dst = &he[ep * FSTR + ((p < 8) ? 0 : 64) + c0];
        dst[0] = f2bf(fa.x); dst[1] = f2bf(fa.y); dst[2] = f2bf(fa.z); dst[3] = f2bf(fa.w);
        dst[4] = f2bf(fb.x); dst[5] = f2bf(fb.y); dst[6] = f2bf(fb.z); dst[7] = f2bf(fb.w);
    }
    __syncthreads();

    const int lane = t & 63, wv = t >> 6, ml = lane & 15, q = lane >> 4;
    float4v acc = {0.f, 0.f, 0.f, 0.f};
    #pragma unroll
    for (int ks = 0; ks < 4; ++ks) {
        const short8 afr = *(const short8*)&he[ml * FSTR + ks * 32 + q * 8];
        const short8 bfr = *(const short8*)&fwT[(16 * wv + ml) * FSTR + ks * 32 + q * 8];
        acc = __builtin_amdgcn_mfma_f32_16x16x32_bf16(afr, bfr, acc, 0, 0, 0);
    }
    const int o = 16 * wv + ml;
    const float bo = b1s[o], wo = w2s[o];
    #pragma unroll
    for (int r = 0; r < 4; ++r) {
        float z = fmaxf(acc[r] + bo, 0.f) * wo;
        z += __shfl_xor(z, 1, 64);
        z += __shfl_xor(z, 2, 64);
        z += __shfl_xor(z, 4, 64);
        z += __shfl_xor(z, 8, 64);
        if (ml == 0) part[q * 4 + r][wv] = z;
    }
    __syncthreads();
    if (t < 16) {
        const float v = part[t][0] + part[t][1] + part[t][2] + part[t][3] + fc2b[0];
        out[b * 2048 + e0 + t] = 1.0f / (1.0f + __expf(-v));
    }
}

// ---------------------------------------------------------------------------
extern "C" void kernel_launch(void* const* d_in, const int* in_sizes, int n_in,
                              void* d_out, int out_size, void* d_ws, size_t ws_size,
                              hipStream_t stream) {
    const float* x    = (const float*)d_in[0];
    const int* adj    = (const int*)d_in[1];
    const int* eidx   = (const int*)d_in[2];
    const float* w1   = (const float*)d_in[3];
    const float* b1   = (const float*)d_in[4];
    const float* w2   = (const float*)d_in[5];
    const float* b2   = (const float*)d_in[6];
    const float* W1   = (const float*)d_in[7];
    const float* a1   = (const float*)d_in[8];
    const float* W2   = (const float*)d_in[9];
    const float* a2   = (const float*)d_in[10];
    const float* fc1w = (const float*)d_in[11];
    const float* fc1b = (const float*)d_in[12];
    const float* fc2w = (const float*)d_in[13];
    const float* fc2b = (const float*)d_in[14];
    float* out = (float*)d_out;

    float* ws = (float*)d_ws;
    const size_t R = (size_t)BATCH * NNODE;       // 4096 rows
    float* hmean = ws;                            // R*64 f32
    float* g1    = hmean + R * 64;                // R*64 f32
    float* f1    = g1 + R * 64;                   // R
    float* f2    = f1 + R;                        // R
    u16*   whbt  = (u16*)(f2 + R);                // R*64 bf16
    float* g2    = hmean;                         // reuse

    conv_fused_kernel<<<dim3(R), dim3(256), 0, stream>>>(x, w1, b1, w2, b2, hmean);
    gat_wh_kernel<<<dim3(64), dim3(256), 0, stream>>>(hmean, W1, a1, whbt, f1, f2);
    gat_attn_kernel<<<dim3(256), dim3(256), 0, stream>>>(whbt, f1, f2, adj, g1, 1);
    gat_wh_kernel<<<dim3(64), dim3(256), 0, stream>>>(g1, W2, a2, whbt, f1, f2);
    gat_attn_kernel<<<dim3(256), dim3(256), 0, stream>>>(whbt, f1, f2, adj, g2, 0);
    edge_mlp_kernel<<<dim3(1024), dim3(256), 0, stream>>>(
        g2, eidx, fc1w, fc1b, fc2w, fc2b, out);
}